// Round 19
// baseline (249.364 us; speedup 1.0000x reference)
//
#include <hip/hip_runtime.h>
#include <math.h>

// L=4096, N=16, H=16, E=64. rho = L*N = 65536 rows of 1024 floats (head h at +64h).
// out[rho][h][f] = exp2( x.Ps[h][:,f] - sq*SQS ) + 1e-6, Ps = proj*64^-.25*log2e.
// proj = q^T D, D = sign(diag(r)) of LAPACK-convention QR(pm[h]^T) (convention-
// dependent — must reproduce geqrf signs). Factor then Q = M R^-1.
// favor: f16 hi/lo split MFMA (C = Xh*Bh + Xh*Bl + Xl*Bh), residual ~2^-23.
// Round-19 = round-18 + prefetch distance 2 (two named register sets, unroll-2
// alternation -> static indexing) + launch_bounds(256,4). r18 counters: low BW
// + low VALU + 26% occupancy = latency-bound; 8 loads in flight per wave
// doubles MLP. nt stores + head-derangement + zero-barrier qr solve retained.

typedef _Float16 f16x8 __attribute__((ext_vector_type(8)));
typedef float    f32x4 __attribute__((ext_vector_type(4)));

#if __has_builtin(__builtin_amdgcn_exp2f)
#define EXP2F(x) __builtin_amdgcn_exp2f(x)
#else
#define EXP2F(x) exp2f(x)
#endif

// ---------------- per-head QR (fp32 Householder, LAPACK dlarfg signs) -------
__global__ __launch_bounds__(256) void qr_kernel(const float* __restrict__ pm,
                                                 float* __restrict__ P)
{
    __shared__ float colb[2][64];
    __shared__ float nrmb[2];
    __shared__ float Rs[64 * 65];
    __shared__ float dval[64];
    __shared__ float dinv[64];
    __shared__ float sgnNZ[64];

    const int tid = threadIdx.x;
    const int h   = blockIdx.x;
    const int c   = tid >> 2;       // column 0..63 (quad = 4 consecutive lanes)
    const int q   = tid & 3;        // row-quarter
    const int i0  = q * 16;

    float A[16];                    // A[k] = M[i0+k][c] = pm[h][c][i0+k]
    {
        const float4* src = reinterpret_cast<const float4*>(pm + h * 4096 + c * 64 + i0);
        #pragma unroll
        for (int k4 = 0; k4 < 4; ++k4) {
            const float4 v = src[k4];
            A[4*k4+0] = v.x; A[4*k4+1] = v.y;
            A[4*k4+2] = v.z; A[4*k4+3] = v.w;
        }
    }
    if (c == 0) {                    // publish column 0 + its sub-norm
        #pragma unroll
        for (int k = 0; k < 16; ++k) colb[0][i0 + k] = A[k];
        float np = 0.f;
        #pragma unroll
        for (int k = 0; k < 16; ++k) if (i0 + k >= 1) np = fmaf(A[k], A[k], np);
        np += __shfl_xor(np, 1); np += __shfl_xor(np, 2);
        if (q == 0) nrmb[0] = np;
    }
    __syncthreads();

    // ---- factor: 64 Householder steps, 1 barrier each ----
    #pragma unroll 1
    for (int j = 0; j < 64; ++j) {
        const float* cbuf = colb[j & 1];
        const float alpha = cbuf[j];
        const float nrm2  = nrmb[j & 1];
        float beta, g;
        if (nrm2 == 0.f) { beta = alpha; g = 0.f; }          // H = I, tau = 0
        else {
            const float an = sqrtf(fmaf(alpha, alpha, nrm2));
            beta = (alpha >= 0.f) ? -an : an;                // -sign(alpha)*norm
            g    = 1.f / (beta * (beta - alpha));            // tau/(alpha-beta)^2
        }
        if (c >= j) {
            float cb[16];
            #pragma unroll
            for (int k = 0; k < 16; ++k) cb[k] = cbuf[i0 + k];
            float wp = 0.f, Ajc = 0.f;
            #pragma unroll
            for (int k = 0; k < 16; ++k) {
                const int i = i0 + k;
                wp  = fmaf((i > j) ? cb[k] : 0.f, A[k], wp); // v0 (i>j) part
                Ajc += (i == j) ? A[k] : 0.f;                // A[j][c]
            }
            wp  += __shfl_xor(wp, 1);  wp  += __shfl_xor(wp, 2);
            Ajc += __shfl_xor(Ajc, 1); Ajc += __shfl_xor(Ajc, 2);
            const float amb = alpha - beta;
            const float gw  = g * (wp + amb * Ajc);          // g * v0^T A[:,c]
            #pragma unroll
            for (int k = 0; k < 16; ++k) {
                const int i = i0 + k;
                const float v0 = (i > j) ? cb[k] : ((i == j) ? amb : 0.f);
                A[k] = fmaf(-gw, v0, A[k]);
            }
            if (c == j + 1) {        // publish next column into the OTHER buffer
                #pragma unroll
                for (int k = 0; k < 16; ++k) colb[(j + 1) & 1][i0 + k] = A[k];
                float np = 0.f;
                #pragma unroll
                for (int k = 0; k < 16; ++k) {
                    const int i = i0 + k;
                    np = fmaf((i > j + 1) ? A[k] : 0.f, A[k], np);
                }
                np += __shfl_xor(np, 1); np += __shfl_xor(np, 2);
                if (q == 0) nrmb[(j + 1) & 1] = np;
            }
        }
        __syncthreads();
    }

    // ---- R to LDS, diag inverses/signs ----
    #pragma unroll
    for (int k = 0; k < 16; ++k) Rs[(i0 + k) * 65 + c] = A[k];
    {
        float dv = 0.f;
        #pragma unroll
        for (int k = 0; k < 16; ++k) dv += (i0 + k == c) ? A[k] : 0.f;
        dv += __shfl_xor(dv, 1); dv += __shfl_xor(dv, 2);
        if (q == 0) dval[c] = dv;
    }
    __syncthreads();
    if (tid < 64) {
        const float d = dval[tid];
        dinv[tid] = 1.f / d;
        const float NZL2E = 0.51012934f;     // 64^-0.25 * log2(e)
        sgnNZ[tid] = (d >= 0.f) ? NZL2E : -NZL2E;
    }
    __syncthreads();

    // ---- solve Q R = M: row-parallel forward substitution, wave 0 only,
    //      ZERO barriers. Lane i owns row i; fully unrolled (static idx).
    if (tid < 64) {
        const int i = tid;
        float r[64];
        #pragma unroll
        for (int c2 = 0; c2 < 64; ++c2)             // row i of M (coalesced)
            r[c2] = pm[h * 4096 + c2 * 64 + i];
        const float sg = sgnNZ[i];
        #pragma unroll
        for (int j = 0; j < 64; ++j) {
            const float qj = r[j] * dinv[j];
            P[h * 4096 + j * 64 + i] = qj * sg;      // P[h][e=j][f=i]
            #pragma unroll
            for (int c2 = j + 1; c2 < 64; ++c2)
                r[c2] = fmaf(-qj, Rs[j * 65 + c2], r[c2]);
        }
    }
}

// -------- FAVOR+ map: direct global->VGPR frags, distance-2 prefetch --------
__global__ __launch_bounds__(256, 4) void favor_kernel(const float* __restrict__ data,
                                                       const float* __restrict__ P,
                                                       float* __restrict__ out)
{
    __shared__ __attribute__((aligned(16))) float SMEM[4096];   // 4 KB/wave scratch

    const int tid   = threadIdx.x;
    const int chunk = blockIdx.x >> 4;              // 0..127
    const int h     = (blockIdx.x + chunk) & 15;    // head-derangement: every
                                                    // XCD sees all 16 offsets
    const size_t rowbase = (size_t)chunk * 512;     // 8 tiles x 64 rows

    const int lane = tid & 63;
    const int wv   = tid >> 6;                      // wave owns rows 16wv..16wv+15
    const int ls   = lane & 15;                     // A-row / C-col
    const int lg   = lane >> 4;                     // k-group

    const float* db = data + (size_t)h * 64;
    const int c0 = lg * 8;                          // lane's k-slice base col

    // A-fragment loads in MFMA lane order: lane (ls,lg) reads row ls,
    // cols c0..c0+7 (kh=0) and 32+c0..32+c0+7 (kh=1): 4x dwordx4.
#define LOADX(T, X) do {                                                           \
        const float* rp_ = db + (rowbase + (size_t)(T) * 64 + 16 * wv + ls) * 1024;\
        (X)[0] = *reinterpret_cast<const float4*>(rp_ + c0);                       \
        (X)[1] = *reinterpret_cast<const float4*>(rp_ + c0 + 4);                   \
        (X)[2] = *reinterpret_cast<const float4*>(rp_ + c0 + 32);                  \
        (X)[3] = *reinterpret_cast<const float4*>(rp_ + c0 + 36);                  \
    } while (0)

    float4 xvA[4], xvB[4];
    LOADX(0, xvA);                                  // prologue: 2 tiles in flight
    LOADX(1, xvB);

    // B fragments straight from global (L1/L2-cached, shared by all blocks of
    // this head). B[k][col]: col = n*16 + ls, k = kh*32 + lg*8 + j.
    f16x8 bh[4][2], bl[4][2];
    #pragma unroll
    for (int n = 0; n < 4; ++n) {
        #pragma unroll
        for (int kh = 0; kh < 2; ++kh) {
            #pragma unroll
            for (int j = 0; j < 8; ++j) {
                const float pv = P[h * 4096 + (kh * 32 + lg * 8 + j) * 64 + n * 16 + ls];
                const _Float16 hi = (_Float16)pv;
                bh[n][kh][j] = hi;
                bl[n][kh][j] = (_Float16)(pv - (float)hi);
            }
        }
    }

    float* strip = SMEM + wv * 1024;                // wave-private 16x64 scratch
    const float SQS = 0.09016844005556021f;         // log2(e)/16

    // one tile's full pipeline: convert xv -> frags, issue prefetch(T+2) into
    // the freed set, 24 MFMAs, LDS C-transpose, 4x nontemporal dwordx4 stores.
#define TILE_BODY(T, XCUR) do {                                                    \
        f16x8 ah[2], al[2];                                                        \
        float sq = 0.f;                                                            \
        _Pragma("unroll")                                                          \
        for (int kh = 0; kh < 2; ++kh) {                                           \
            const float xs[8] = {XCUR[2*kh].x, XCUR[2*kh].y,                       \
                                 XCUR[2*kh].z, XCUR[2*kh].w,                       \
                                 XCUR[2*kh+1].x, XCUR[2*kh+1].y,                   \
                                 XCUR[2*kh+1].z, XCUR[2*kh+1].w};                  \
            _Pragma("unroll")                                                      \
            for (int j = 0; j < 8; ++j) {                                          \
                const float x = xs[j];                                             \
                const _Float16 hi = (_Float16)x;                                   \
                ah[kh][j] = hi;                                                    \
                al[kh][j] = (_Float16)(x - (float)hi);                             \
                sq = fmaf(x, x, sq);                                               \
            }                                                                      \
        }                                                                          \
        if ((T) + 2 < 8) LOADX((T) + 2, XCUR);      /* refill freed set */         \
        sq += __shfl_xor(sq, 16);                                                  \
        sq += __shfl_xor(sq, 32);                   /* valid for row ls */         \
        f32x4 acc[4];                                                              \
        _Pragma("unroll")                                                          \
        for (int n = 0; n < 4; ++n) {                                              \
            f32x4 a = {0.f, 0.f, 0.f, 0.f};                                        \
            _Pragma("unroll")                                                      \
            for (int kh = 0; kh < 2; ++kh) {                                       \
                a = __builtin_amdgcn_mfma_f32_16x16x32_f16(ah[kh], bh[n][kh], a, 0, 0, 0); \
                a = __builtin_amdgcn_mfma_f32_16x16x32_f16(ah[kh], bl[n][kh], a, 0, 0, 0); \
                a = __builtin_amdgcn_mfma_f32_16x16x32_f16(al[kh], bh[n][kh], a, 0, 0, 0); \
            }                                                                      \
            acc[n] = a;                                                            \
        }                                                                          \
        _Pragma("unroll")                                                          \
        for (int reg = 0; reg < 4; ++reg) {                                        \
            const int row_i = 4 * lg + reg;                                        \
            const float sqr = __shfl(sq, row_i) * SQS;                             \
            _Pragma("unroll")                                                      \
            for (int n = 0; n < 4; ++n)                                            \
                strip[row_i * 64 + ((16 * n + ls) ^ (lg << 4))] =                  \
                    EXP2F(acc[n][reg] - sqr) + 1e-6f;                              \
        }                                                                          \
        asm volatile("s_waitcnt lgkmcnt(0)" ::: "memory");                         \
        const size_t rowT = rowbase + (size_t)(T) * 64 + 16 * wv;                  \
        _Pragma("unroll")                                                          \
        for (int s = 0; s < 4; ++s) {                                              \
            const int row = 4 * s + lg;                                            \
            const f32x4 v = *reinterpret_cast<const f32x4*>(                       \
                strip + row * 64 + ((4 * ls) ^ (s << 4)));                         \
            __builtin_nontemporal_store(v, reinterpret_cast<f32x4*>(               \
                out + (rowT + (size_t)row) * 1024 + (size_t)h * 64 + 4 * ls));     \
        }                                                                          \
        asm volatile("s_waitcnt lgkmcnt(0)" ::: "memory");                         \
    } while (0)

    #pragma unroll 1
    for (int tp = 0; tp < 4; ++tp) {                // 2 tiles per iteration:
        const int t0 = 2 * tp;                      // static set alternation
        TILE_BODY(t0, xvA);
        TILE_BODY(t0 + 1, xvB);
    }
#undef TILE_BODY
#undef LOADX
}

extern "C" void kernel_launch(void* const* d_in, const int* in_sizes, int n_in,
                              void* d_out, int out_size, void* d_ws, size_t ws_size,
                              hipStream_t stream)
{
    const float* data = (const float*)d_in[0];   // (L,N,H,E) fp32
    const float* pm   = (const float*)d_in[1];   // (H,E,E)   fp32
    float* out = (float*)d_out;                  // (L,N,H,F) fp32
    float* P   = (float*)d_ws;                   // 16*64*64*4 = 256 KB scratch

    qr_kernel<<<16, 256, 0, stream>>>(pm, P);
    favor_kernel<<<2048, 256, 0, stream>>>(data, P, out);
}

// Round 20
// 148.386 us; speedup vs baseline: 1.6805x; 1.6805x over previous
//
#include <hip/hip_runtime.h>
#include <math.h>

// L=4096, N=16, H=16, E=64. rho = L*N = 65536 rows of 1024 floats (head h at +64h).
// out[rho][h][f] = exp2( x.Ps[h][:,f] - sq*SQS ) + 1e-6, Ps = proj*64^-.25*log2e.
// proj = q^T D, D = sign(diag(r)) of LAPACK-convention QR(pm[h]^T) (convention-
// dependent — must reproduce geqrf signs). Factor then Q = M R^-1.
// favor: f16 hi/lo split MFMA (C = Xh*Bh + Xh*Bl + Xl*Bh), residual ~2^-23.
// Round-20 = round-19's distance-2 prefetch with round-18's launch_bounds
// (256,3). r19's (256,4) clamped VGPR to 64 -> spills (FETCH 134->355MB,
// WRITE 262->332MB = scratch traffic) which buried the MLP experiment.
// nt stores + head-derangement + zero-barrier qr solve retained.

typedef _Float16 f16x8 __attribute__((ext_vector_type(8)));
typedef float    f32x4 __attribute__((ext_vector_type(4)));

#if __has_builtin(__builtin_amdgcn_exp2f)
#define EXP2F(x) __builtin_amdgcn_exp2f(x)
#else
#define EXP2F(x) exp2f(x)
#endif

// ---------------- per-head QR (fp32 Householder, LAPACK dlarfg signs) -------
__global__ __launch_bounds__(256) void qr_kernel(const float* __restrict__ pm,
                                                 float* __restrict__ P)
{
    __shared__ float colb[2][64];
    __shared__ float nrmb[2];
    __shared__ float Rs[64 * 65];
    __shared__ float dval[64];
    __shared__ float dinv[64];
    __shared__ float sgnNZ[64];

    const int tid = threadIdx.x;
    const int h   = blockIdx.x;
    const int c   = tid >> 2;       // column 0..63 (quad = 4 consecutive lanes)
    const int q   = tid & 3;        // row-quarter
    const int i0  = q * 16;

    float A[16];                    // A[k] = M[i0+k][c] = pm[h][c][i0+k]
    {
        const float4* src = reinterpret_cast<const float4*>(pm + h * 4096 + c * 64 + i0);
        #pragma unroll
        for (int k4 = 0; k4 < 4; ++k4) {
            const float4 v = src[k4];
            A[4*k4+0] = v.x; A[4*k4+1] = v.y;
            A[4*k4+2] = v.z; A[4*k4+3] = v.w;
        }
    }
    if (c == 0) {                    // publish column 0 + its sub-norm
        #pragma unroll
        for (int k = 0; k < 16; ++k) colb[0][i0 + k] = A[k];
        float np = 0.f;
        #pragma unroll
        for (int k = 0; k < 16; ++k) if (i0 + k >= 1) np = fmaf(A[k], A[k], np);
        np += __shfl_xor(np, 1); np += __shfl_xor(np, 2);
        if (q == 0) nrmb[0] = np;
    }
    __syncthreads();

    // ---- factor: 64 Householder steps, 1 barrier each ----
    #pragma unroll 1
    for (int j = 0; j < 64; ++j) {
        const float* cbuf = colb[j & 1];
        const float alpha = cbuf[j];
        const float nrm2  = nrmb[j & 1];
        float beta, g;
        if (nrm2 == 0.f) { beta = alpha; g = 0.f; }          // H = I, tau = 0
        else {
            const float an = sqrtf(fmaf(alpha, alpha, nrm2));
            beta = (alpha >= 0.f) ? -an : an;                // -sign(alpha)*norm
            g    = 1.f / (beta * (beta - alpha));            // tau/(alpha-beta)^2
        }
        if (c >= j) {
            float cb[16];
            #pragma unroll
            for (int k = 0; k < 16; ++k) cb[k] = cbuf[i0 + k];
            float wp = 0.f, Ajc = 0.f;
            #pragma unroll
            for (int k = 0; k < 16; ++k) {
                const int i = i0 + k;
                wp  = fmaf((i > j) ? cb[k] : 0.f, A[k], wp); // v0 (i>j) part
                Ajc += (i == j) ? A[k] : 0.f;                // A[j][c]
            }
            wp  += __shfl_xor(wp, 1);  wp  += __shfl_xor(wp, 2);
            Ajc += __shfl_xor(Ajc, 1); Ajc += __shfl_xor(Ajc, 2);
            const float amb = alpha - beta;
            const float gw  = g * (wp + amb * Ajc);          // g * v0^T A[:,c]
            #pragma unroll
            for (int k = 0; k < 16; ++k) {
                const int i = i0 + k;
                const float v0 = (i > j) ? cb[k] : ((i == j) ? amb : 0.f);
                A[k] = fmaf(-gw, v0, A[k]);
            }
            if (c == j + 1) {        // publish next column into the OTHER buffer
                #pragma unroll
                for (int k = 0; k < 16; ++k) colb[(j + 1) & 1][i0 + k] = A[k];
                float np = 0.f;
                #pragma unroll
                for (int k = 0; k < 16; ++k) {
                    const int i = i0 + k;
                    np = fmaf((i > j + 1) ? A[k] : 0.f, A[k], np);
                }
                np += __shfl_xor(np, 1); np += __shfl_xor(np, 2);
                if (q == 0) nrmb[(j + 1) & 1] = np;
            }
        }
        __syncthreads();
    }

    // ---- R to LDS, diag inverses/signs ----
    #pragma unroll
    for (int k = 0; k < 16; ++k) Rs[(i0 + k) * 65 + c] = A[k];
    {
        float dv = 0.f;
        #pragma unroll
        for (int k = 0; k < 16; ++k) dv += (i0 + k == c) ? A[k] : 0.f;
        dv += __shfl_xor(dv, 1); dv += __shfl_xor(dv, 2);
        if (q == 0) dval[c] = dv;
    }
    __syncthreads();
    if (tid < 64) {
        const float d = dval[tid];
        dinv[tid] = 1.f / d;
        const float NZL2E = 0.51012934f;     // 64^-0.25 * log2(e)
        sgnNZ[tid] = (d >= 0.f) ? NZL2E : -NZL2E;
    }
    __syncthreads();

    // ---- solve Q R = M: row-parallel forward substitution, wave 0 only,
    //      ZERO barriers. Lane i owns row i; fully unrolled (static idx).
    if (tid < 64) {
        const int i = tid;
        float r[64];
        #pragma unroll
        for (int c2 = 0; c2 < 64; ++c2)             // row i of M (coalesced)
            r[c2] = pm[h * 4096 + c2 * 64 + i];
        const float sg = sgnNZ[i];
        #pragma unroll
        for (int j = 0; j < 64; ++j) {
            const float qj = r[j] * dinv[j];
            P[h * 4096 + j * 64 + i] = qj * sg;      // P[h][e=j][f=i]
            #pragma unroll
            for (int c2 = j + 1; c2 < 64; ++c2)
                r[c2] = fmaf(-qj, Rs[j * 65 + c2], r[c2]);
        }
    }
}

// -------- FAVOR+ map: direct global->VGPR frags, distance-2 prefetch --------
__global__ __launch_bounds__(256, 3) void favor_kernel(const float* __restrict__ data,
                                                       const float* __restrict__ P,
                                                       float* __restrict__ out)
{
    __shared__ __attribute__((aligned(16))) float SMEM[4096];   // 4 KB/wave scratch

    const int tid   = threadIdx.x;
    const int chunk = blockIdx.x >> 4;              // 0..127
    const int h     = (blockIdx.x + chunk) & 15;    // head-derangement: every
                                                    // XCD sees all 16 offsets
    const size_t rowbase = (size_t)chunk * 512;     // 8 tiles x 64 rows

    const int lane = tid & 63;
    const int wv   = tid >> 6;                      // wave owns rows 16wv..16wv+15
    const int ls   = lane & 15;                     // A-row / C-col
    const int lg   = lane >> 4;                     // k-group

    const float* db = data + (size_t)h * 64;
    const int c0 = lg * 8;                          // lane's k-slice base col

    // A-fragment loads in MFMA lane order: lane (ls,lg) reads row ls,
    // cols c0..c0+7 (kh=0) and 32+c0..32+c0+7 (kh=1): 4x dwordx4.
#define LOADX(T, X) do {                                                           \
        const float* rp_ = db + (rowbase + (size_t)(T) * 64 + 16 * wv + ls) * 1024;\
        (X)[0] = *reinterpret_cast<const float4*>(rp_ + c0);                       \
        (X)[1] = *reinterpret_cast<const float4*>(rp_ + c0 + 4);                   \
        (X)[2] = *reinterpret_cast<const float4*>(rp_ + c0 + 32);                  \
        (X)[3] = *reinterpret_cast<const float4*>(rp_ + c0 + 36);                  \
    } while (0)

    float4 xvA[4], xvB[4];
    LOADX(0, xvA);                                  // prologue: 2 tiles in flight
    LOADX(1, xvB);

    // B fragments straight from global (L1/L2-cached, shared by all blocks of
    // this head). B[k][col]: col = n*16 + ls, k = kh*32 + lg*8 + j.
    f16x8 bh[4][2], bl[4][2];
    #pragma unroll
    for (int n = 0; n < 4; ++n) {
        #pragma unroll
        for (int kh = 0; kh < 2; ++kh) {
            #pragma unroll
            for (int j = 0; j < 8; ++j) {
                const float pv = P[h * 4096 + (kh * 32 + lg * 8 + j) * 64 + n * 16 + ls];
                const _Float16 hi = (_Float16)pv;
                bh[n][kh][j] = hi;
                bl[n][kh][j] = (_Float16)(pv - (float)hi);
            }
        }
    }

    float* strip = SMEM + wv * 1024;                // wave-private 16x64 scratch
    const float SQS = 0.09016844005556021f;         // log2(e)/16

    // one tile's full pipeline: convert xv -> frags, issue prefetch(T+2) into
    // the freed set, 24 MFMAs, LDS C-transpose, 4x nontemporal dwordx4 stores.
#define TILE_BODY(T, XCUR) do {                                                    \
        f16x8 ah[2], al[2];                                                        \
        float sq = 0.f;                                                            \
        _Pragma("unroll")                                                          \
        for (int kh = 0; kh < 2; ++kh) {                                           \
            const float xs[8] = {XCUR[2*kh].x, XCUR[2*kh].y,                       \
                                 XCUR[2*kh].z, XCUR[2*kh].w,                       \
                                 XCUR[2*kh+1].x, XCUR[2*kh+1].y,                   \
                                 XCUR[2*kh+1].z, XCUR[2*kh+1].w};                  \
            _Pragma("unroll")                                                      \
            for (int j = 0; j < 8; ++j) {                                          \
                const float x = xs[j];                                             \
                const _Float16 hi = (_Float16)x;                                   \
                ah[kh][j] = hi;                                                    \
                al[kh][j] = (_Float16)(x - (float)hi);                             \
                sq = fmaf(x, x, sq);                                               \
            }                                                                      \
        }                                                                          \
        if ((T) + 2 < 8) LOADX((T) + 2, XCUR);      /* refill freed set */         \
        sq += __shfl_xor(sq, 16);                                                  \
        sq += __shfl_xor(sq, 32);                   /* valid for row ls */         \
        f32x4 acc[4];                                                              \
        _Pragma("unroll")                                                          \
        for (int n = 0; n < 4; ++n) {                                              \
            f32x4 a = {0.f, 0.f, 0.f, 0.f};                                        \
            _Pragma("unroll")                                                      \
            for (int kh = 0; kh < 2; ++kh) {                                       \
                a = __builtin_amdgcn_mfma_f32_16x16x32_f16(ah[kh], bh[n][kh], a, 0, 0, 0); \
                a = __builtin_amdgcn_mfma_f32_16x16x32_f16(ah[kh], bl[n][kh], a, 0, 0, 0); \
                a = __builtin_amdgcn_mfma_f32_16x16x32_f16(al[kh], bh[n][kh], a, 0, 0, 0); \
            }                                                                      \
            acc[n] = a;                                                            \
        }                                                                          \
        _Pragma("unroll")                                                          \
        for (int reg = 0; reg < 4; ++reg) {                                        \
            const int row_i = 4 * lg + reg;                                        \
            const float sqr = __shfl(sq, row_i) * SQS;                             \
            _Pragma("unroll")                                                      \
            for (int n = 0; n < 4; ++n)                                            \
                strip[row_i * 64 + ((16 * n + ls) ^ (lg << 4))] =                  \
                    EXP2F(acc[n][reg] - sqr) + 1e-6f;                              \
        }                                                                          \
        asm volatile("s_waitcnt lgkmcnt(0)" ::: "memory");                         \
        const size_t rowT = rowbase + (size_t)(T) * 64 + 16 * wv;                  \
        _Pragma("unroll")                                                          \
        for (int s = 0; s < 4; ++s) {                                              \
            const int row = 4 * s + lg;                                            \
            const f32x4 v = *reinterpret_cast<const f32x4*>(                       \
                strip + row * 64 + ((4 * ls) ^ (s << 4)));                         \
            __builtin_nontemporal_store(v, reinterpret_cast<f32x4*>(               \
                out + (rowT + (size_t)row) * 1024 + (size_t)h * 64 + 4 * ls));     \
        }                                                                          \
        asm volatile("s_waitcnt lgkmcnt(0)" ::: "memory");                         \
    } while (0)

    #pragma unroll 1
    for (int tp = 0; tp < 4; ++tp) {                // 2 tiles per iteration:
        const int t0 = 2 * tp;                      // static set alternation
        TILE_BODY(t0, xvA);
        TILE_BODY(t0 + 1, xvB);
    }
#undef TILE_BODY
#undef LOADX
}

extern "C" void kernel_launch(void* const* d_in, const int* in_sizes, int n_in,
                              void* d_out, int out_size, void* d_ws, size_t ws_size,
                              hipStream_t stream)
{
    const float* data = (const float*)d_in[0];   // (L,N,H,E) fp32
    const float* pm   = (const float*)d_in[1];   // (H,E,E)   fp32
    float* out = (float*)d_out;                  // (L,N,H,F) fp32
    float* P   = (float*)d_ws;                   // 16*64*64*4 = 256 KB scratch

    qr_kernel<<<16, 256, 0, stream>>>(pm, P);
    favor_kernel<<<2048, 256, 0, stream>>>(data, P, out);
}